// Round 6
// baseline (333.017 us; speedup 1.0000x reference)
//
#include <hip/hip_runtime.h>
#include <hip/hip_fp16.h>

// MPM P2G: cell buckets (16B quantized records) + LDS-tile gather-scatter.
//
// node[g] = sum over particles in cells {g-1,g}^3 of trilinear w * (m, m*v)
// cell/node id: z + x*128 + y*128*128   (reference get_hash, dim==3)
//
// Pipeline (4 dispatches):
//   M  memset : cursors (8MB) + ovf_cnt, one contiguous memset
//   K1 place  : atomicAdd(cursor[cell]) -> slot; 16B record
//               {fx,fy,fz u16 fixed-point, m,vx,vy,vz fp16}. CAP=4 -> 64B/cell.
//   K2 tile   : block per 16x8x16 NODE tile; scan 17x9x17 CELL halo
//               (1.27x visits/record vs 8x in node-per-thread gather),
//               unpack once, scatter 8 corners via LDS atomics, drop corners
//               outside owned region (neighbor tile owns them), coalesced
//               float4 writeout. No atomics / memset on d_out.
//   K3 fixup  : rare bucket-overflow particles, exact fp32 atomic scatter.
// Fallbacks: R3 counting-sort pipeline, then naive scatter.

#define GRID_DIM   128
#define NUM_CELLS  (GRID_DIM * GRID_DIM * GRID_DIM)   // 2,097,152
#define INV_CELL   64.0f
#define OVF_MAX    65536
#define SCAN_BLKS  2048

// node tile dims (z is the fast/coalesced axis)
#define TX 16
#define TY 8
#define TZ 16
#define HX (TX + 1)   // 17
#define HY (TY + 1)   // 9
#define HZ (TZ + 1)   // 17
#define NCELLS_HALO (HX * HY * HZ)          // 2601
#define NTILE_X (GRID_DIM / TX)             // 8
#define NTILE_Y (GRID_DIM / TY)             // 16
#define NTILE_Z (GRID_DIM / TZ)             // 8
#define NTILES  (NTILE_X * NTILE_Y * NTILE_Z) // 1024

__device__ __forceinline__ int cell_id(int ix, int iy, int iz) {
    return iz + ix * GRID_DIM + iy * (GRID_DIM * GRID_DIM);
}

__device__ __forceinline__ unsigned int q16(float f) {
    int q = (int)(f * 65536.0f + 0.5f);
    return (unsigned int)min(q, 65535);
}
__device__ __forceinline__ unsigned int f2h(float f) {
    return (unsigned int)__half_as_ushort(__float2half(f));
}
__device__ __forceinline__ float h2f(unsigned int b) {
    return __half2float(__ushort_as_half((unsigned short)(b & 0xffffu)));
}

// ---- K1: bucket placement (single atomic pass) ----------------------------
__global__ __launch_bounds__(256) void bucket_place_kernel(
    const float* __restrict__ pos, const float* __restrict__ vel,
    const float* __restrict__ mass, unsigned int* __restrict__ cursors,
    uint4* __restrict__ buckets, int* __restrict__ ovf_cnt,
    int* __restrict__ ovf_list, int cap, int n)
{
    int i = blockIdx.x * 256 + threadIdx.x;
    if (i >= n) return;
    float rx = pos[3 * i + 0] * INV_CELL;
    float ry = pos[3 * i + 1] * INV_CELL;
    float rz = pos[3 * i + 2] * INV_CELL;
    float bx = floorf(rx), by = floorf(ry), bz = floorf(rz);
    float fx = rx - bx, fy = ry - by, fz = rz - bz;   // in [0,1)
    int ix = min(max((int)bx, 0), GRID_DIM - 1);
    int iy = min(max((int)by, 0), GRID_DIM - 1);
    int iz = min(max((int)bz, 0), GRID_DIM - 1);
    int c = cell_id(ix, iy, iz);
    unsigned int s = atomicAdd(&cursors[c], 1u);
    if (s < (unsigned int)cap) {
        uint4 r;
        r.x = q16(fx) | (q16(fy) << 16);
        r.y = q16(fz) | (f2h(mass[i]) << 16);
        r.z = f2h(vel[3 * i + 0]) | (f2h(vel[3 * i + 1]) << 16);
        r.w = f2h(vel[3 * i + 2]);
        buckets[c * cap + (int)s] = r;
    } else {
        int o = atomicAdd(ovf_cnt, 1);
        if (o < OVF_MAX) ovf_list[o] = i;
    }
}

// ---- K2: LDS-tile gather-scatter ------------------------------------------
__global__ __launch_bounds__(256) void tile_gather_kernel(
    const uint4* __restrict__ buckets, const unsigned int* __restrict__ cursors,
    float4* __restrict__ out, int cap)
{
    __shared__ float acc[TX * TY * TZ * 4];   // 32 KB
    int tid = threadIdx.x;
    int b = blockIdx.x;
    int tz = b & (NTILE_Z - 1);
    int tx = (b >> 3) & (NTILE_X - 1);
    int ty = b >> 6;
    int ox = tx * TX, oy = ty * TY, oz = tz * TZ;

    for (int q = tid; q < TX * TY * TZ; q += 256)
        ((float4*)acc)[q] = make_float4(0.f, 0.f, 0.f, 0.f);
    __syncthreads();

    for (int ci = tid; ci < NCELLS_HALO; ci += 256) {
        int t = ci;
        int hz = t % HZ; t /= HZ;
        int hx = t % HX; t /= HX;
        int hy = t;
        int cx = ox - 1 + hx;
        int cy = oy - 1 + hy;
        int cz = oz - 1 + hz;
        if ((unsigned)cx >= (unsigned)GRID_DIM ||
            (unsigned)cy >= (unsigned)GRID_DIM ||
            (unsigned)cz >= (unsigned)GRID_DIM) continue;
        int c = cell_id(cx, cy, cz);
        int cnt = (int)cursors[c];
        if (cnt == 0) continue;
        cnt = min(cnt, cap);
        int base = c * cap;
        int lx0 = cx - ox, ly0 = cy - oy, lz0 = cz - oz;   // in [-1, T-1]
        for (int j = 0; j < cnt; ++j) {
            uint4 r = buckets[base + j];
            float fx = (float)(r.x & 0xffffu) * (1.0f / 65536.0f);
            float fy = (float)(r.x >> 16)     * (1.0f / 65536.0f);
            float fz = (float)(r.y & 0xffffu) * (1.0f / 65536.0f);
            float m  = h2f(r.y >> 16);
            float vx = h2f(r.z), vy = h2f(r.z >> 16), vz = h2f(r.w);
            float wxm[2] = { (1.0f - fx) * m, fx * m };
            float wy2[2] = { 1.0f - fy, fy };
            float wz2[2] = { 1.0f - fz, fz };
            #pragma unroll
            for (int a = 0; a < 2; ++a) {
                #pragma unroll
                for (int b2 = 0; b2 < 2; ++b2) {
                    #pragma unroll
                    for (int c2 = 0; c2 < 2; ++c2) {
                        int lx = lx0 + a, ly = ly0 + b2, lz = lz0 + c2;
                        if ((unsigned)lx < (unsigned)TX &&
                            (unsigned)ly < (unsigned)TY &&
                            (unsigned)lz < (unsigned)TZ) {
                            float sm = wxm[a] * wy2[b2] * wz2[c2];
                            int idx = (((ly * TX + lx) * TZ) + lz) * 4;
                            atomicAdd(&acc[idx + 0], sm);
                            atomicAdd(&acc[idx + 1], sm * vx);
                            atomicAdd(&acc[idx + 2], sm * vy);
                            atomicAdd(&acc[idx + 3], sm * vz);
                        }
                    }
                }
            }
        }
    }
    __syncthreads();

    // every node owned by exactly one tile: plain coalesced stores, no memset
    for (int q = tid; q < TX * TY * TZ; q += 256) {
        int lz = q & (TZ - 1);
        int lx = (q >> 4) & (TX - 1);
        int ly = q >> 8;
        float4 v = ((const float4*)acc)[((ly * TX + lx) * TZ) + lz];
        out[(oz + lz) + (ox + lx) * GRID_DIM + (oy + ly) * (GRID_DIM * GRID_DIM)] = v;
    }
}

// ---- K3: overflow fixup (exact fp32, rare) --------------------------------
__global__ __launch_bounds__(256) void fixup_kernel(
    const float* __restrict__ pos, const float* __restrict__ vel,
    const float* __restrict__ mass, const int* __restrict__ ovf_cnt,
    const int* __restrict__ ovf_list, float* __restrict__ out)
{
    int total = min(*ovf_cnt, OVF_MAX);
    for (int k = blockIdx.x * 256 + threadIdx.x; k < total; k += gridDim.x * 256) {
        int i = ovf_list[k];
        float px = pos[3 * i + 0] * INV_CELL;
        float py = pos[3 * i + 1] * INV_CELL;
        float pz = pos[3 * i + 2] * INV_CELL;
        float bx = floorf(px), by = floorf(py), bz = floorf(pz);
        float fx = px - bx, fy = py - by, fz = pz - bz;
        int ix = (int)bx, iy = (int)by, iz = (int)bz;
        float m = mass[i];
        float vx = vel[3 * i + 0], vy = vel[3 * i + 1], vz = vel[3 * i + 2];
        float wx[2] = { 1.0f - fx, fx }, wy[2] = { 1.0f - fy, fy }, wz[2] = { 1.0f - fz, fz };
        #pragma unroll
        for (int a = 0; a < 2; ++a)
            #pragma unroll
            for (int b = 0; b < 2; ++b)
                #pragma unroll
                for (int c = 0; c < 2; ++c) {
                    int h = cell_id(ix + a, iy + b, iz + c);
                    bool valid = (h >= 0) && (h < NUM_CELLS);
                    int hc = min(max(h, 0), NUM_CELLS - 1);
                    float s = valid ? (wx[a] * wy[b] * wz[c]) : 0.0f;
                    float sm = s * m;
                    float* cell = out + 4 * (size_t)hc;
                    atomicAdd(cell + 0, sm);
                    atomicAdd(cell + 1, sm * vx);
                    atomicAdd(cell + 2, sm * vy);
                    atomicAdd(cell + 3, sm * vz);
                }
    }
}

// ======== fallback: R3 counting-sort pipeline (verified 228us) =============
__global__ __launch_bounds__(256) void s_hist_kernel(
    const float* __restrict__ pos, int* __restrict__ counts, int n)
{
    int i = blockIdx.x * 256 + threadIdx.x;
    if (i >= n) return;
    int ix = min(max((int)floorf(pos[3 * i + 0] * INV_CELL), 0), GRID_DIM - 1);
    int iy = min(max((int)floorf(pos[3 * i + 1] * INV_CELL), 0), GRID_DIM - 1);
    int iz = min(max((int)floorf(pos[3 * i + 2] * INV_CELL), 0), GRID_DIM - 1);
    atomicAdd(&counts[cell_id(ix, iy, iz)], 1);
}

__global__ __launch_bounds__(256) void s_scan_partials_kernel(
    const int* __restrict__ counts, int* __restrict__ partials)
{
    __shared__ int red[256];
    int t = threadIdx.x;
    int4 v = ((const int4*)counts)[blockIdx.x * 256 + t];
    red[t] = v.x + v.y + v.z + v.w;
    __syncthreads();
    for (int off = 128; off > 0; off >>= 1) {
        if (t < off) red[t] += red[t + off];
        __syncthreads();
    }
    if (t == 0) partials[blockIdx.x] = red[0];
}

__global__ __launch_bounds__(1024) void s_scan_tops_kernel(int* __restrict__ partials)
{
    __shared__ int s[1024];
    int t = threadIdx.x;
    int p0 = partials[2 * t], p1 = partials[2 * t + 1];
    int sum = p0 + p1;
    s[t] = sum;
    __syncthreads();
    for (int off = 1; off < 1024; off <<= 1) {
        int x = (t >= off) ? s[t - off] : 0;
        __syncthreads();
        s[t] += x;
        __syncthreads();
    }
    int excl = s[t] - sum;
    partials[2 * t] = excl;
    partials[2 * t + 1] = excl + p0;
}

__global__ __launch_bounds__(256) void s_scan_final_kernel(
    const int* __restrict__ counts, const int* __restrict__ partials,
    int* __restrict__ offsets, int* __restrict__ cursors)
{
    __shared__ int s[256];
    int t = threadIdx.x;
    int g = blockIdx.x * 256 + t;
    int4 v = ((const int4*)counts)[g];
    int sum = v.x + v.y + v.z + v.w;
    s[t] = sum;
    __syncthreads();
    for (int off = 1; off < 256; off <<= 1) {
        int x = (t >= off) ? s[t - off] : 0;
        __syncthreads();
        s[t] += x;
        __syncthreads();
    }
    int run = partials[blockIdx.x] + s[t] - sum;
    int4 o = make_int4(run, run + v.x, run + v.x + v.y, run + v.x + v.y + v.z);
    ((int4*)offsets)[g] = o;
    ((int4*)cursors)[g] = o;
}

__global__ __launch_bounds__(256) void s_binplace_kernel(
    const float* __restrict__ pos, const float* __restrict__ vel,
    const float* __restrict__ mass, int* __restrict__ cursors,
    float4* __restrict__ records, int n)
{
    int i = blockIdx.x * 256 + threadIdx.x;
    if (i >= n) return;
    float rx = pos[3 * i + 0] * INV_CELL;
    float ry = pos[3 * i + 1] * INV_CELL;
    float rz = pos[3 * i + 2] * INV_CELL;
    int ix = min(max((int)floorf(rx), 0), GRID_DIM - 1);
    int iy = min(max((int)floorf(ry), 0), GRID_DIM - 1);
    int iz = min(max((int)floorf(rz), 0), GRID_DIM - 1);
    int slot = atomicAdd(&cursors[cell_id(ix, iy, iz)], 1);
    records[2 * slot + 0] = make_float4(rx, ry, rz, mass[i]);
    records[2 * slot + 1] = make_float4(vel[3 * i + 0], vel[3 * i + 1],
                                        vel[3 * i + 2], 0.0f);
}

__global__ __launch_bounds__(256) void s_node_gather_kernel(
    const float4* __restrict__ records, const int* __restrict__ offsets,
    const int* __restrict__ cursors, float4* __restrict__ out)
{
    int id = blockIdx.x * 256 + threadIdx.x;
    int gz = id & (GRID_DIM - 1);
    int gx = (id >> 7) & (GRID_DIM - 1);
    int gy = id >> 14;
    float fgx = (float)gx, fgy = (float)gy, fgz = (float)gz;
    float a0 = 0.0f, a1 = 0.0f, a2 = 0.0f, a3 = 0.0f;
    int z0 = max(gz - 1, 0), y0 = max(gy - 1, 0), x0 = max(gx - 1, 0);
    for (int cy = y0; cy <= gy; ++cy) {
        for (int cx = x0; cx <= gx; ++cx) {
            int cb = cx * GRID_DIM + cy * (GRID_DIM * GRID_DIM);
            int beg = offsets[cb + z0];
            int end = cursors[cb + gz];
            for (int p = beg; p < end; ++p) {
                float4 r0 = records[2 * p + 0];
                float4 r1 = records[2 * p + 1];
                float w = (1.0f - fabsf(r0.x - fgx)) *
                          (1.0f - fabsf(r0.y - fgy)) *
                          (1.0f - fabsf(r0.z - fgz));
                float sm = w * r0.w;
                a0 += sm; a1 += sm * r1.x; a2 += sm * r1.y; a3 += sm * r1.z;
            }
        }
    }
    out[id] = make_float4(a0, a1, a2, a3);
}

// ---- last-resort naive scatter --------------------------------------------
__global__ __launch_bounds__(256) void p2g_scatter_kernel(
    const float* __restrict__ pos, const float* __restrict__ vel,
    const float* __restrict__ mass, float* __restrict__ out, int n)
{
    int i = blockIdx.x * blockDim.x + threadIdx.x;
    if (i >= n) return;
    float px = pos[3 * i + 0] * INV_CELL;
    float py = pos[3 * i + 1] * INV_CELL;
    float pz = pos[3 * i + 2] * INV_CELL;
    float bx = floorf(px), by = floorf(py), bz = floorf(pz);
    float fx = px - bx, fy = py - by, fz = pz - bz;
    int ix = (int)bx, iy = (int)by, iz = (int)bz;
    float m = mass[i];
    float vx = vel[3 * i + 0], vy = vel[3 * i + 1], vz = vel[3 * i + 2];
    float wx[2] = { 1.0f - fx, fx }, wy[2] = { 1.0f - fy, fy }, wz[2] = { 1.0f - fz, fz };
    #pragma unroll
    for (int a = 0; a < 2; ++a)
        #pragma unroll
        for (int b = 0; b < 2; ++b)
            #pragma unroll
            for (int c = 0; c < 2; ++c) {
                int h = cell_id(ix + a, iy + b, iz + c);
                bool valid = (h >= 0) && (h < NUM_CELLS);
                int hc = min(max(h, 0), NUM_CELLS - 1);
                float s = valid ? (wx[a] * wy[b] * wz[c]) : 0.0f;
                float sm = s * m;
                float* cell = out + 4 * (size_t)hc;
                atomicAdd(cell + 0, sm);
                atomicAdd(cell + 1, sm * vx);
                atomicAdd(cell + 2, sm * vy);
                atomicAdd(cell + 3, sm * vz);
            }
}

extern "C" void kernel_launch(void* const* d_in, const int* in_sizes, int n_in,
                              void* d_out, int out_size, void* d_ws, size_t ws_size,
                              hipStream_t stream) {
    const float* pos  = (const float*)d_in[0];
    const float* vel  = (const float*)d_in[1];
    const float* mass = (const float*)d_in[2];
    float* out = (float*)d_out;
    int n = in_sizes[2];
    int blocks = (n + 255) / 256;

    // Bucket-path ws: [cursors 8MB][ovf_cnt 256B][ovf_list 256KB][buckets]
    size_t off_ovfc = (size_t)NUM_CELLS * 4;
    size_t off_ovfl = off_ovfc + 256;
    size_t off_bkt  = off_ovfl + (size_t)OVF_MAX * 4;
    auto bucket_need = [&](int cap) {
        return off_bkt + (size_t)NUM_CELLS * cap * 16;
    };
    int cap = 0;
    if (ws_size >= bucket_need(4))      cap = 4;
    else if (ws_size >= bucket_need(3)) cap = 3;

    // Sorted-path ws: [counts/cursors 8MB][offsets 8MB][records n*32][partials]
    size_t s_off_offsets  = (size_t)NUM_CELLS * 4;
    size_t s_off_records  = s_off_offsets + (size_t)NUM_CELLS * 4;
    size_t s_off_partials = s_off_records + (size_t)n * 32;
    size_t need_sorted    = s_off_partials + (size_t)SCAN_BLKS * 4;

    if (cap > 0) {
        char* ws = (char*)d_ws;
        unsigned int* cursors = (unsigned int*)ws;
        int* ovf_cnt  = (int*)(ws + off_ovfc);
        int* ovf_list = (int*)(ws + off_ovfl);
        uint4* buckets = (uint4*)(ws + off_bkt);

        // one memset covers cursors + ovf_cnt (contiguous)
        hipMemsetAsync(cursors, 0, off_ovfc + 256, stream);
        bucket_place_kernel<<<blocks, 256, 0, stream>>>(
            pos, vel, mass, cursors, buckets, ovf_cnt, ovf_list, cap, n);
        tile_gather_kernel<<<NTILES, 256, 0, stream>>>(
            buckets, cursors, (float4*)out, cap);
        fixup_kernel<<<32, 256, 0, stream>>>(pos, vel, mass, ovf_cnt,
                                             ovf_list, out);
    } else if (ws_size >= need_sorted) {
        char* ws = (char*)d_ws;
        int* counts   = (int*)ws;                    // reused as cursors
        int* offsets  = (int*)(ws + s_off_offsets);
        float4* records = (float4*)(ws + s_off_records);
        int* partials = (int*)(ws + s_off_partials);

        hipMemsetAsync(counts, 0, (size_t)NUM_CELLS * 4, stream);
        s_hist_kernel<<<blocks, 256, 0, stream>>>(pos, counts, n);
        s_scan_partials_kernel<<<SCAN_BLKS, 256, 0, stream>>>(counts, partials);
        s_scan_tops_kernel<<<1, 1024, 0, stream>>>(partials);
        s_scan_final_kernel<<<SCAN_BLKS, 256, 0, stream>>>(counts, partials,
                                                           offsets, counts);
        s_binplace_kernel<<<blocks, 256, 0, stream>>>(pos, vel, mass, counts,
                                                      records, n);
        s_node_gather_kernel<<<NUM_CELLS / 256, 256, 0, stream>>>(
            records, offsets, counts, (float4*)out);
    } else {
        hipMemsetAsync(out, 0, (size_t)out_size * sizeof(float), stream);
        p2g_scatter_kernel<<<blocks, 256, 0, stream>>>(pos, vel, mass, out, n);
    }
}